// Round 3
// baseline (946.035 us; speedup 1.0000x reference)
//
#include <hip/hip_runtime.h>

#define NTOK 16384

typedef short          bf16x8 __attribute__((ext_vector_type(8)));
typedef float          f32x4  __attribute__((ext_vector_type(4)));
typedef unsigned short u16x4  __attribute__((ext_vector_type(4)));

// ws float offsets (total 788480 floats ~= 3.08 MB, proven-available footprint)
#define WHI_OFF 0         // 768*256 ushort
#define WLO_OFF 98304     // 768*256 ushort
#define CTX_OFF 196608    // 65536 floats (atomic ctx numerator, [b][h][c][d])
#define Z_OFF   262144    // 2048 floats  (atomic z sums)
#define MHI_OFF 264192    // 8*256*256 ushort
#define MLO_OFF 526336    // 8*256*256 ushort

union UB8 { unsigned u[4]; bf16x8 v; };

__device__ __forceinline__ void split2(float v0, float v1, unsigned& hi, unsigned& lo) {
    unsigned b0 = __float_as_uint(v0), b1 = __float_as_uint(v1);
    unsigned h0 = b0 & 0xffff0000u, h1 = b1 & 0xffff0000u;
    hi = (b0 >> 16) | h1;
    float r0 = v0 - __uint_as_float(h0);
    float r1 = v1 - __uint_as_float(h1);
    lo = (__float_as_uint(r0) >> 16) | (__float_as_uint(r1) & 0xffff0000u);
}
__device__ __forceinline__ unsigned short bf16_trunc(float v) {
    return (unsigned short)(__float_as_uint(v) >> 16);
}

__global__ void splitw_k(const float* __restrict__ w,
                         unsigned short* __restrict__ whi,
                         unsigned short* __restrict__ wlo)
{
    const int gid = blockIdx.x * 256 + threadIdx.x;   // 24576 threads x 8 elems
    const float4* wp = (const float4*)w;
    float4 a = wp[gid * 2], b = wp[gid * 2 + 1];
    unsigned h0, h1, h2, h3, l0, l1, l2, l3;
    split2(a.x, a.y, h0, l0);
    split2(a.z, a.w, h1, l1);
    split2(b.x, b.y, h2, l2);
    split2(b.z, b.w, h3, l3);
    ((uint4*)whi)[gid] = make_uint4(h0, h1, h2, h3);
    ((uint4*)wlo)[gid] = make_uint4(l0, l1, l2, l3);
}

// K_A: 512 blocks x 512 thr. Block = 256 tokens = 8 chunks of 32.
// Per chunk: GEMM kv[512ch][32tok] via MFMA split-3; B-frags from LDS-staged
// pre-split x (double-buffered 64-ch slabs); epilogue -> bf16 kvt[ch][tok]
// (swizzled); context ctx^T[d][c] += v . ek^T per head (wave==head) + z via
// ones-MFMA. Atomic flush once per block.
__launch_bounds__(512, 4)
__global__ void kv_ctx_k(const float* __restrict__ x,
                         const unsigned short* __restrict__ whi,
                         const unsigned short* __restrict__ wlo,
                         const float* __restrict__ bqkv,
                         float* __restrict__ ctxn, float* __restrict__ zsum)
{
    __shared__ unsigned short kvt[512 * 32];       // 32 KB [ch][tok^swz]
    __shared__ unsigned short xsh[2][32 * 64];     // 2x4 KB [tok][ch^swz] hi
    __shared__ unsigned short xsl[2][32 * 64];     // 2x4 KB lo

    const int tid  = threadIdx.x;
    const int wave = tid >> 6, lane = tid & 63;
    const int quad = lane >> 4, l16 = lane & 15;
    const int b = blockIdx.x >> 6, tile = blockIdx.x & 63;
    const float* xb = x + (size_t)b * 256 * NTOK;
    const int stok = tid & 31, sc4 = tid >> 5;     // staging task: 1 per thread
    const int h = wave;                            // wave == head for context

    f32x4 cacc[2][2];                              // [mi=d-tile][ni=c-tile]
    f32x4 zacc[2];
#pragma unroll
    for (int mi = 0; mi < 2; ++mi)
#pragma unroll
        for (int ni = 0; ni < 2; ++ni) cacc[mi][ni] = (f32x4){0.f, 0.f, 0.f, 0.f};
    zacc[0] = zacc[1] = (f32x4){0.f, 0.f, 0.f, 0.f};
    bf16x8 ones;
#pragma unroll
    for (int j = 0; j < 8; ++j) ones[j] = (short)0x3F80;

    for (int chunk = 0; chunk < 8; ++chunk) {
        const int n0 = tile * 256 + chunk * 32;

        auto stage = [&](int slab, int buf) {
            const int k0 = slab * 64;
            const float* xp = xb + (size_t)(k0 + sc4 * 4) * NTOK + n0 + stok;
            float v0 = xp[0], v1 = xp[NTOK], v2 = xp[2 * NTOK], v3 = xp[3 * NTOK];
            unsigned h0, l0, h1, l1;
            split2(v0, v1, h0, l0);
            split2(v2, v3, h1, l1);
            const int e = (sc4 * 4) ^ ((stok & 7) << 3);
            *(uint2*)&xsh[buf][stok * 64 + e] = make_uint2(h0, h1);
            *(uint2*)&xsl[buf][stok * 64 + e] = make_uint2(l0, l1);
        };

        f32x4 acc[4][2];
#pragma unroll
        for (int rt = 0; rt < 4; ++rt)
#pragma unroll
            for (int ct = 0; ct < 2; ++ct) acc[rt][ct] = (f32x4){0.f, 0.f, 0.f, 0.f};

        stage(0, 0);
        __syncthreads();
        for (int s = 0; s < 4; ++s) {
            if (s < 3) stage(s + 1, (s + 1) & 1);
            const unsigned short* xh = xsh[s & 1];
            const unsigned short* xl = xsl[s & 1];
#pragma unroll
            for (int kk = 0; kk < 2; ++kk) {
                const int k0 = s * 64 + kk * 32;
                bf16x8 ah[4], al[4];
#pragma unroll
                for (int rt = 0; rt < 4; ++rt) {
                    const int off = (256 + wave * 64 + rt * 16 + l16) * 256 + k0 + quad * 8;
                    ah[rt] = *(const bf16x8*)(whi + off);
                    al[rt] = *(const bf16x8*)(wlo + off);
                }
                bf16x8 bh[2], bl[2];
#pragma unroll
                for (int ct = 0; ct < 2; ++ct) {
                    const int t = ct * 16 + l16;
                    const int e = (kk * 32 + quad * 8) ^ ((t & 7) << 3);
                    bh[ct] = *(const bf16x8*)&xh[t * 64 + e];
                    bl[ct] = *(const bf16x8*)&xl[t * 64 + e];
                }
#pragma unroll
                for (int rt = 0; rt < 4; ++rt)
#pragma unroll
                    for (int ct = 0; ct < 2; ++ct) {
                        acc[rt][ct] = __builtin_amdgcn_mfma_f32_16x16x32_bf16(ah[rt], bh[ct], acc[rt][ct], 0, 0, 0);
                        acc[rt][ct] = __builtin_amdgcn_mfma_f32_16x16x32_bf16(al[rt], bh[ct], acc[rt][ct], 0, 0, 0);
                        acc[rt][ct] = __builtin_amdgcn_mfma_f32_16x16x32_bf16(ah[rt], bl[ct], acc[rt][ct], 0, 0, 0);
                    }
            }
            __syncthreads();
        }

        // epilogue: bias (+exp for k rows: waves 0-3), bf16, swizzled kvt store
#pragma unroll
        for (int rt = 0; rt < 4; ++rt) {
            const int ch0 = wave * 64 + rt * 16 + quad * 4;
            const float4 bq = *(const float4*)(bqkv + 256 + ch0);
            const float bias[4] = {bq.x, bq.y, bq.z, bq.w};
            const int swz = ((ch0 >> 2) & 3) << 3;
#pragma unroll
            for (int ct = 0; ct < 2; ++ct) {
                const int tp = (ct * 16 + l16) ^ swz;
#pragma unroll
                for (int r = 0; r < 4; ++r) {
                    float val = acc[rt][ct][r] + bias[r];
                    if (wave < 4) val = __expf(val);
                    kvt[(ch0 + r) * 32 + tp] = bf16_trunc(val);
                }
            }
        }
        __syncthreads();

        // context: ctx^T[d][c] += v . ek^T ; z += ones . ek  (K = 32 tokens)
        {
            const int swz = ((l16 >> 2) & 3) << 3;
            const int tcol = (quad * 8) ^ swz;
            bf16x8 av[2], be[2];
#pragma unroll
            for (int mi = 0; mi < 2; ++mi)
                av[mi] = *(const bf16x8*)&kvt[(256 + h * 32 + mi * 16 + l16) * 32 + tcol];
#pragma unroll
            for (int ni = 0; ni < 2; ++ni)
                be[ni] = *(const bf16x8*)&kvt[(h * 32 + ni * 16 + l16) * 32 + tcol];
#pragma unroll
            for (int mi = 0; mi < 2; ++mi)
#pragma unroll
                for (int ni = 0; ni < 2; ++ni)
                    cacc[mi][ni] = __builtin_amdgcn_mfma_f32_16x16x32_bf16(av[mi], be[ni], cacc[mi][ni], 0, 0, 0);
#pragma unroll
            for (int ni = 0; ni < 2; ++ni)
                zacc[ni] = __builtin_amdgcn_mfma_f32_16x16x32_bf16(ones, be[ni], zacc[ni], 0, 0, 0);
        }
        // no barrier needed: next write to kvt is after >=5 barriers
    }

    float* cp = ctxn + (size_t)(b * 8 + h) * 1024;
#pragma unroll
    for (int mi = 0; mi < 2; ++mi)
#pragma unroll
        for (int ni = 0; ni < 2; ++ni)
#pragma unroll
            for (int r = 0; r < 4; ++r) {
                const int c = ni * 16 + l16;             // ctx^T: rows=d, cols=c
                const int d = mi * 16 + quad * 4 + r;
                atomicAdd(&cp[c * 32 + d], cacc[mi][ni][r]);
            }
    if (quad == 0) {
#pragma unroll
        for (int ni = 0; ni < 2; ++ni)
            atomicAdd(&zsum[(b * 8 + h) * 32 + ni * 16 + l16], zacc[ni][0]);
    }
}

// K_B: M[b][o][h*32+c] = sum_d w_out[o][h*32+d] * (ctxn[b,h,c,d]/z[b,h,c]) -> hi/lo bf16
__global__ void build_m_k(const float* __restrict__ ctxn, const float* __restrict__ zsum,
                          const float* __restrict__ wout,
                          unsigned short* __restrict__ mhi, unsigned short* __restrict__ mlo)
{
    __shared__ float cl[1024];
    __shared__ float zl[32];
    const int b = blockIdx.x >> 3, h = blockIdx.x & 7;
    const int tid = threadIdx.x;
    if (tid < 32) zl[tid] = 1.0f / zsum[(b * 8 + h) * 32 + tid];
    __syncthreads();
    for (int i = tid; i < 1024; i += 256)
        cl[i] = ctxn[(size_t)(b * 8 + h) * 1024 + i] * zl[i >> 5];
    __syncthreads();
    const int o = tid;
    float wrow[32];
#pragma unroll
    for (int d = 0; d < 32; ++d) wrow[d] = wout[o * 256 + h * 32 + d];
    float m[32];
#pragma unroll 4
    for (int c = 0; c < 32; ++c) {
        float acc = 0.f;
#pragma unroll
        for (int d = 0; d < 32; ++d) acc += wrow[d] * cl[c * 32 + d];
        m[c] = acc;
    }
    unsigned* ph = (unsigned*)(mhi + (size_t)b * 65536 + o * 256 + h * 32);
    unsigned* pl = (unsigned*)(mlo + (size_t)b * 65536 + o * 256 + h * 32);
#pragma unroll
    for (int p = 0; p < 16; ++p) {
        unsigned hu, lu;
        split2(m[2 * p], m[2 * p + 1], hu, lu);
        ph[p] = hu; pl[p] = lu;
    }
}

// K_C: 2048 blocks x 512 thr, 64 tokens/block. GEMM1 q (split-3, staged x) ->
// register softmax (shfl over quads) -> bf16 qb LDS -> GEMM2 (M hi/lo) -> out.
__launch_bounds__(512, 4)
__global__ void final_k(const float* __restrict__ x,
                        const unsigned short* __restrict__ whi,
                        const unsigned short* __restrict__ wlo,
                        const float* __restrict__ bqkv,
                        const unsigned short* __restrict__ mhi,
                        const unsigned short* __restrict__ mlo,
                        const float* __restrict__ bout, float* __restrict__ out)
{
    __shared__ unsigned short qb[64 * 256];        // 32 KB [tok][ch^swz]
    __shared__ unsigned short xsh[2][64 * 64];     // 2x8 KB [tok][ch^swz] hi
    __shared__ unsigned short xsl[2][64 * 64];     // 2x8 KB lo

    const int tid  = threadIdx.x;
    const int wave = tid >> 6, lane = tid & 63;
    const int quad = lane >> 4, l16 = lane & 15;
    const int rw = wave & 3, tg = wave >> 2;       // row-group / token-half
    const int b = blockIdx.x >> 8, tile = blockIdx.x & 255;
    const int n0 = tile * 64;
    const float* xb = x + (size_t)b * 256 * NTOK;

    auto stage = [&](int slab, int buf) {
        const int k0 = slab * 64;
#pragma unroll
        for (int rep = 0; rep < 2; ++rep) {
            const int tau = tid + rep * 512;
            const int tok = tau & 63, c4 = tau >> 6;
            const float* xp = xb + (size_t)(k0 + c4 * 4) * NTOK + n0 + tok;
            float v0 = xp[0], v1 = xp[NTOK], v2 = xp[2 * NTOK], v3 = xp[3 * NTOK];
            unsigned h0, l0, h1, l1;
            split2(v0, v1, h0, l0);
            split2(v2, v3, h1, l1);
            const int e = (c4 * 4) ^ ((tok & 7) << 3);
            *(uint2*)&xsh[buf][tok * 64 + e] = make_uint2(h0, h1);
            *(uint2*)&xsl[buf][tok * 64 + e] = make_uint2(l0, l1);
        }
    };

    // ---- GEMM1: q[256][64], wave tile 64 rows x 32 tok ----
    f32x4 acc[4][2];
#pragma unroll
    for (int rt = 0; rt < 4; ++rt)
#pragma unroll
        for (int ct = 0; ct < 2; ++ct) acc[rt][ct] = (f32x4){0.f, 0.f, 0.f, 0.f};

    stage(0, 0);
    __syncthreads();
    for (int s = 0; s < 4; ++s) {
        if (s < 3) stage(s + 1, (s + 1) & 1);
        const unsigned short* xh = xsh[s & 1];
        const unsigned short* xl = xsl[s & 1];
#pragma unroll
        for (int kk = 0; kk < 2; ++kk) {
            const int k0 = s * 64 + kk * 32;
            bf16x8 ah[4], al[4];
#pragma unroll
            for (int rt = 0; rt < 4; ++rt) {
                const int off = (rw * 64 + rt * 16 + l16) * 256 + k0 + quad * 8;
                ah[rt] = *(const bf16x8*)(whi + off);
                al[rt] = *(const bf16x8*)(wlo + off);
            }
            bf16x8 bh[2], bl[2];
#pragma unroll
            for (int ct = 0; ct < 2; ++ct) {
                const int t = tg * 32 + ct * 16 + l16;
                const int e = (kk * 32 + quad * 8) ^ ((t & 7) << 3);
                bh[ct] = *(const bf16x8*)&xh[t * 64 + e];
                bl[ct] = *(const bf16x8*)&xl[t * 64 + e];
            }
#pragma unroll
            for (int rt = 0; rt < 4; ++rt)
#pragma unroll
                for (int ct = 0; ct < 2; ++ct) {
                    acc[rt][ct] = __builtin_amdgcn_mfma_f32_16x16x32_bf16(ah[rt], bh[ct], acc[rt][ct], 0, 0, 0);
                    acc[rt][ct] = __builtin_amdgcn_mfma_f32_16x16x32_bf16(al[rt], bh[ct], acc[rt][ct], 0, 0, 0);
                    acc[rt][ct] = __builtin_amdgcn_mfma_f32_16x16x32_bf16(ah[rt], bl[ct], acc[rt][ct], 0, 0, 0);
                }
        }
        __syncthreads();
    }

    // ---- softmax over 32 channels/head in registers; pack bf16 -> qb ----
#pragma unroll
    for (int rt = 0; rt < 4; ++rt) {
        const int ch0 = rw * 64 + rt * 16 + quad * 4;
        const float4 bq = *(const float4*)(bqkv + ch0);
        const float bias[4] = {bq.x, bq.y, bq.z, bq.w};
#pragma unroll
        for (int ct = 0; ct < 2; ++ct)
#pragma unroll
            for (int r = 0; r < 4; ++r)
                acc[rt][ct][r] = __expf(acc[rt][ct][r] + bias[r]);
    }
#pragma unroll
    for (int hh = 0; hh < 2; ++hh) {          // head = 2*rw + hh, rt in {2hh,2hh+1}
#pragma unroll
        for (int ct = 0; ct < 2; ++ct) {
            float s = 0.f;
#pragma unroll
            for (int rr = 0; rr < 2; ++rr)
#pragma unroll
                for (int r = 0; r < 4; ++r) s += acc[hh * 2 + rr][ct][r];
            s += __shfl_xor(s, 16);
            s += __shfl_xor(s, 32);
            const float rinv = 1.0f / s;
            const int t = tg * 32 + ct * 16 + l16;
            const int sw = (t & 7) << 3;
#pragma unroll
            for (int rr = 0; rr < 2; ++rr) {
                const int rt = hh * 2 + rr;
                const int ch0 = rw * 64 + rt * 16 + quad * 4;
                u16x4 st;
#pragma unroll
                for (int r = 0; r < 4; ++r) st[r] = bf16_trunc(acc[rt][ct][r] * rinv);
                *(u16x4*)&qb[t * 256 + (ch0 ^ sw)] = st;
            }
        }
    }
    __syncthreads();

    // ---- GEMM2: out[256][64] = M (hi/lo) x q_s ----
    f32x4 acc2[4][2];
#pragma unroll
    for (int rt = 0; rt < 4; ++rt)
#pragma unroll
        for (int ct = 0; ct < 2; ++ct) acc2[rt][ct] = (f32x4){0.f, 0.f, 0.f, 0.f};
    const unsigned short* mhb = mhi + (size_t)b * 65536;
    const unsigned short* mlb = mlo + (size_t)b * 65536;

    for (int k0 = 0; k0 < 256; k0 += 32) {
        bf16x8 ah[4], al[4];
#pragma unroll
        for (int rt = 0; rt < 4; ++rt) {
            const int off = (rw * 64 + rt * 16 + l16) * 256 + k0 + quad * 8;
            ah[rt] = *(const bf16x8*)(mhb + off);
            al[rt] = *(const bf16x8*)(mlb + off);
        }
        bf16x8 bq[2];
#pragma unroll
        for (int ct = 0; ct < 2; ++ct) {
            const int t = tg * 32 + ct * 16 + l16;
            bq[ct] = *(const bf16x8*)&qb[t * 256 + ((k0 + quad * 8) ^ ((t & 7) << 3))];
        }
#pragma unroll
        for (int rt = 0; rt < 4; ++rt)
#pragma unroll
            for (int ct = 0; ct < 2; ++ct) {
                acc2[rt][ct] = __builtin_amdgcn_mfma_f32_16x16x32_bf16(ah[rt], bq[ct], acc2[rt][ct], 0, 0, 0);
                acc2[rt][ct] = __builtin_amdgcn_mfma_f32_16x16x32_bf16(al[rt], bq[ct], acc2[rt][ct], 0, 0, 0);
            }
    }

    float* ob = out + (size_t)b * 256 * NTOK;
#pragma unroll
    for (int rt = 0; rt < 4; ++rt) {
        const int o0 = rw * 64 + rt * 16 + quad * 4;
        const float4 bo = *(const float4*)(bout + o0);
        const float bof[4] = {bo.x, bo.y, bo.z, bo.w};
#pragma unroll
        for (int ct = 0; ct < 2; ++ct) {
            const int t = tg * 32 + ct * 16 + l16;
#pragma unroll
            for (int r = 0; r < 4; ++r)
                ob[(size_t)(o0 + r) * NTOK + n0 + t] = acc2[rt][ct][r] + bof[r];
        }
    }
}

extern "C" void kernel_launch(void* const* d_in, const int* in_sizes, int n_in,
                              void* d_out, int out_size, void* d_ws, size_t ws_size,
                              hipStream_t stream)
{
    (void)in_sizes; (void)n_in; (void)out_size; (void)ws_size;
    const float* x    = (const float*)d_in[0];
    const float* wqkv = (const float*)d_in[1];
    const float* bqkv = (const float*)d_in[2];
    const float* wout = (const float*)d_in[3];
    const float* bout = (const float*)d_in[4];
    float* out = (float*)d_out;
    float* ws  = (float*)d_ws;

    unsigned short* whi = (unsigned short*)(ws + WHI_OFF);
    unsigned short* wlo = (unsigned short*)(ws + WLO_OFF);
    float*          ctx = ws + CTX_OFF;
    float*          zs  = ws + Z_OFF;
    unsigned short* mhi = (unsigned short*)(ws + MHI_OFF);
    unsigned short* mlo = (unsigned short*)(ws + MLO_OFF);

    hipMemsetAsync(ctx, 0, (65536 + 2048) * sizeof(float), stream);
    splitw_k<<<96, 256, 0, stream>>>(wqkv, whi, wlo);
    kv_ctx_k<<<512, 512, 0, stream>>>(x, whi, wlo, bqkv, ctx, zs);
    build_m_k<<<64, 256, 0, stream>>>(ctx, zs, wout, mhi, mlo);
    final_k<<<2048, 512, 0, stream>>>(x, whi, wlo, bqkv, mhi, mlo, bout, out);
}